// Round 6
// baseline (174.142 us; speedup 1.0000x reference)
//
#include <hip/hip_runtime.h>

// Conv2d 3x3 s1 p1, N=16 C=64 H=W=112 F=64, fp32 in/out, bf16 MFMA implicit GEMM.
// R10: 3 independent blocks per CU (revert R9's pin/pmod/lgkm bundle).
//  - 256-thread blocks (4 waves: r x nh), strips of 4 rows = 2 tiles.
//  - NPL=6 LDS planes = 51.5 KB -> 3 blocks/CU = 3 waves/SIMD from THREE
//    independent blocks: one block's barrier/vmcnt drain hides under the other
//    two blocks' tap loops (R8 had 2 waves/SIMD from ONE block -> lockstep).
//  - A strip's 6 live rows (hb-1..hb+4) fit the 6 planes exactly: plane =
//    row-hb+1, no ring wrap, no modulo.
//  - Keeps R8's proven pieces: async stage split (loads before taps, convert+
//    ds_write after), pitch-67 bank-uniform LDS, direct float4 epilogue,
//    plain __syncthreads (2 per block).
// grid (16,2,28) = 896 blocks; linear id % 8 == n % 8 -> image n's halo-row
// re-reads stay on one XCD's L2.

typedef __attribute__((ext_vector_type(8))) short bf16x8;
typedef __attribute__((ext_vector_type(4))) float f32x4;

#define CIN 64
#define COUT 64
#define HH 112
#define WW 112
#define NPL 6                     // planes: rows hb-1..hb+4, never wraps
#define WPITCH 67                 // 16B-unit bank residue (3*oct+w)&7 uniform
#define PLANE_SHORTS (8 * WPITCH * 8)     // 4288 shorts = 8576 B
#define LDS_SHORTS (NPL * PLANE_SHORTS)   // 25728 shorts = 51456 B -> 3 blocks/CU

__device__ __forceinline__ int ladr(int pl, int oct, int w) {
    // bf16 [plane][oct][wcol][8ch]; addr in shorts.
    return ((pl * 8 + oct) * WPITCH + w) * 8;
}

__device__ __forceinline__ unsigned short f2bf(float f) {
    unsigned u = __builtin_bit_cast(unsigned, f);
    u += 0x7FFFu + ((u >> 16) & 1u);   // round-to-nearest-even
    return (unsigned short)(u >> 16);
}

#if __has_builtin(__builtin_amdgcn_cvt_pk_bf16_f32)
__device__ __forceinline__ unsigned pk2bf(float a, float b) {
    typedef __attribute__((ext_vector_type(2))) __bf16 bf16x2;
    bf16x2 r = __builtin_amdgcn_cvt_pk_bf16_f32(a, b);
    return __builtin_bit_cast(unsigned, r);
}
#else
__device__ __forceinline__ unsigned pk2bf(float a, float b) {
    return (unsigned)f2bf(a) | ((unsigned)f2bf(b) << 16);
}
#endif

// ---- one-time weight conversion: OIHW fp32 -> bf16 [t][cb][koct][f][j] ----
__global__ void conv_wprep(const float* __restrict__ w, short* __restrict__ wbf) {
    int i = blockIdx.x * 256 + threadIdx.x;    // grid sized to exactly 36864
    int j = i & 7;
    int f = (i >> 3) & 63;
    int koct = (i >> 9) & 3;
    int cb = (i >> 11) & 1;
    int t = i >> 12;
    int c = cb * 32 + koct * 8 + j;
    int ky = t / 3, kx = t - ky * 3;
    wbf[i] = (short)f2bf(w[((f * CIN + c) * 3 + ky) * 3 + kx]);
}

struct StageRegs {
    float4 v[8];   // interior unit: 8 channels x 4 cols
    float hv;      // halo-column value
};

// Issue global loads for rows row0, row0+1 into regs (unit: re=tid>>7, oct, w4).
// Rows outside [0,HH) stay zero (the padding the taps expect).
__device__ __forceinline__ void stage_load(const float* __restrict__ x, int tid,
                                           int n, int c0, int W4N, int gce,
                                           int row0, StageRegs& sr)
{
    const int re  = tid >> 7;          // 0..1
    const int oct = (tid >> 4) & 7;
    const int w4  = tid & 15;
    const int row = row0 + re;
#pragma unroll
    for (int k = 0; k < 8; ++k) sr.v[k] = (float4){0.f, 0.f, 0.f, 0.f};
    sr.hv = 0.f;
    if ((unsigned)row < (unsigned)HH && w4 < W4N) {
        const float* px = x + (((n * CIN + oct * 8) * HH + row) * WW + c0 + w4 * 4);
#pragma unroll
        for (int k = 0; k < 8; ++k) sr.v[k] = *(const float4*)(px + k * HH * WW);
    }
    const int hrow = row0 + (tid >> 6);         // halo: tid<128 covers 2 rows x 64ch
    if (tid < 128 && (unsigned)hrow < (unsigned)HH)
        sr.hv = x[((n * CIN + (tid & 63)) * HH + hrow) * WW + gce];
}

// Convert + write staged rows into planes pl0, pl0+1.
__device__ __forceinline__ void stage_write(short* lds, int tid, int W4N,
                                            int padw, int wedge, int pl0,
                                            const StageRegs& sr)
{
    const int re  = tid >> 7;
    const int oct = (tid >> 4) & 7;
    const int w4  = tid & 15;
    if (w4 < W4N) {
        const int pl = pl0 + re;
        const float* fv = (const float*)&sr.v[0];
#pragma unroll
        for (int dw = 0; dw < 4; ++dw) {
            uint4 pk;
            pk.x = pk2bf(fv[0 * 4 + dw], fv[1 * 4 + dw]);
            pk.y = pk2bf(fv[2 * 4 + dw], fv[3 * 4 + dw]);
            pk.z = pk2bf(fv[4 * 4 + dw], fv[5 * 4 + dw]);
            pk.w = pk2bf(fv[6 * 4 + dw], fv[7 * 4 + dw]);
            *(uint4*)&lds[ladr(pl, oct, 1 + w4 * 4 + dw)] = pk;
        }
    }
    if (tid < 128) {                   // halo column
        const int pl = pl0 + (tid >> 6);
        const int c = tid & 63;
        lds[ladr(pl, c >> 3, wedge) + (c & 7)] = (short)f2bf(sr.hv);
    }
    if (tid < 16) {                    // pad column zero: 2 rows x 8 octs
        const int pl = pl0 + (tid >> 3);
        *(uint4*)&lds[ladr(pl, tid & 7, padw)] = (uint4){0u, 0u, 0u, 0u};
    }
}

// One 2-row output tile: 9 taps x MTN mt x 4 MFMA, then direct stores.
// Taps read planes plbase+ky (plbase = r for tile0, r+2 for tile1).
__device__ __forceinline__ void tile_compute(const short* lds,
    const bf16x8 (&bw)[9][2], float* __restrict__ out,
    int n, int c0, int MTN, int h0, int plbase, int lm, int q,
    int f0, float b0, float b1)
{
    f32x4 acc[4][2];
#pragma unroll
    for (int mt = 0; mt < 4; ++mt)
#pragma unroll
        for (int ntl = 0; ntl < 2; ++ntl) acc[mt][ntl] = (f32x4){0.f, 0.f, 0.f, 0.f};

#pragma unroll
    for (int tap = 0; tap < 9; ++tap) {
        const int ky = tap / 3, kx = tap - ky * 3;
        const int pl = plbase + ky;
#pragma unroll
        for (int mt = 0; mt < 4; ++mt) {
            if (mt < MTN) {
                const int wcol = mt * 16 + lm + kx;
                const bf16x8 a0 = *(const bf16x8*)&lds[ladr(pl, q, wcol)];
                const bf16x8 a1 = *(const bf16x8*)&lds[ladr(pl, q + 4, wcol)];
                acc[mt][0] = __builtin_amdgcn_mfma_f32_16x16x32_bf16(a0, bw[tap][0], acc[mt][0], 0, 0, 0);
                acc[mt][1] = __builtin_amdgcn_mfma_f32_16x16x32_bf16(a0, bw[tap][1], acc[mt][1], 0, 0, 0);
                // second K-half: weights at cb=1 live in the paired frag set
                const bf16x8 b2 = bw[tap][0], b3 = bw[tap][1]; (void)b2; (void)b3;
                acc[mt][0] = acc[mt][0];  // placeholder removed below
            }
        }
    }
    // NOTE: restructured below — see full tap loop in caller-visible version.
    (void)out; (void)n; (void)c0; (void)h0; (void)lm; (void)q; (void)f0; (void)b0; (void)b1;
}

// ---- real tile computation (kept in one place; the stub above is unused) ----
__device__ __forceinline__ void tile_run(const short* lds,
    const bf16x8 (&bw)[9][2][2], float* __restrict__ out,
    int n, int c0, int MTN, int h0, int plbase, int r, int lm, int q,
    int f0, float b0, float b1)
{
    f32x4 acc[4][2];
#pragma unroll
    for (int mt = 0; mt < 4; ++mt)
#pragma unroll
        for (int ntl = 0; ntl < 2; ++ntl) acc[mt][ntl] = (f32x4){0.f, 0.f, 0.f, 0.f};

#pragma unroll
    for (int tap = 0; tap < 9; ++tap) {
        const int ky = tap / 3, kx = tap - ky * 3;
        const int pl = plbase + ky;
#pragma unroll
        for (int mt = 0; mt < 4; ++mt) {
            if (mt < MTN) {
                const int wcol = mt * 16 + lm + kx;
                const bf16x8 a0 = *(const bf16x8*)&lds[ladr(pl, q, wcol)];
                const bf16x8 a1 = *(const bf16x8*)&lds[ladr(pl, q + 4, wcol)];
                acc[mt][0] = __builtin_amdgcn_mfma_f32_16x16x32_bf16(a0, bw[tap][0][0], acc[mt][0], 0, 0, 0);
                acc[mt][1] = __builtin_amdgcn_mfma_f32_16x16x32_bf16(a0, bw[tap][1][0], acc[mt][1], 0, 0, 0);
                acc[mt][0] = __builtin_amdgcn_mfma_f32_16x16x32_bf16(a1, bw[tap][0][1], acc[mt][0], 0, 0, 0);
                acc[mt][1] = __builtin_amdgcn_mfma_f32_16x16x32_bf16(a1, bw[tap][1][1], acc[mt][1], 0, 0, 0);
            }
        }
    }

    const int hrow = h0 + r;
#pragma unroll
    for (int mt = 0; mt < 4; ++mt) {
        if (mt < MTN) {
#pragma unroll
            for (int ntl = 0; ntl < 2; ++ntl) {
                const f32x4 v = acc[mt][ntl];
                const float bb = ntl ? b1 : b0;
                float4 s;
                s.x = v[0] + bb; s.y = v[1] + bb; s.z = v[2] + bb; s.w = v[3] + bb;
                *(float4*)(out + ((n * COUT + f0 + ntl * 16) * HH + hrow) * WW
                           + c0 + mt * 16 + q * 4) = s;
            }
        }
    }
}

__global__ __launch_bounds__(256, 3)
void conv3x3_mfma(const float* __restrict__ x, const short* __restrict__ wbf,
                  const float* __restrict__ bias, float* __restrict__ out)
{
    __shared__ __align__(16) short lds[LDS_SHORTS];
    const int tid = threadIdx.x;
    const int n = blockIdx.x;
    const int ws = blockIdx.y;          // 0: out cols 0..63; 1: cols 64..111
    const int hb = blockIdx.z * 4;      // 4-row strip = 2 tiles

    const int MTN   = ws ? 3 : 4;
    const int W4N   = ws ? 12 : 16;
    const int c0    = ws * 64;
    const int padw  = ws ? 49 : 0;
    const int gce   = ws ? 63 : 64;
    const int wedge = ws ? 0 : 65;

    const int wave = tid >> 6;         // 0..3
    const int r  = wave >> 1;          // output row within tile (0..1)
    const int nh = wave & 1;           // cout half
    const int lane = tid & 63;
    const int lm = lane & 15;
    const int q  = lane >> 4;

    // ---- prologue: rows hb-1..hb+2 -> planes 0..3 (two buffers, loads overlap) ----
    {
        StageRegs sA, sB;
        stage_load(x, tid, n, c0, W4N, gce, hb - 1, sA);
        stage_load(x, tid, n, c0, W4N, gce, hb + 1, sB);
        stage_write(lds, tid, W4N, padw, wedge, 0, sA);
        stage_write(lds, tid, W4N, padw, wedge, 2, sB);
    }

    // ---- B preload: 9 taps x 2 ntl x 2 cb fragments ----
    bf16x8 bw[9][2][2];
#pragma unroll
    for (int t = 0; t < 9; ++t)
#pragma unroll
        for (int ntl = 0; ntl < 2; ++ntl) {
            const int f = nh * 32 + ntl * 16 + lm;
            bw[t][ntl][0] = *(const bf16x8*)(wbf + (t * 8 + q) * 512 + f * 8);
            bw[t][ntl][1] = *(const bf16x8*)(wbf + (t * 8 + 4 + q) * 512 + f * 8);
        }

    const int f0 = nh * 32 + lm;
    const float b0 = bias[f0];
    const float b1 = bias[f0 + 16];

    __syncthreads();

    // ---- tile 0: prefetch rows hb+3,hb+4 under the taps ----
    StageRegs sr;
    stage_load(x, tid, n, c0, W4N, gce, hb + 3, sr);
    tile_run(lds, bw, out, n, c0, MTN, hb, /*plbase=*/r, r, lm, q, f0, b0, b1);
    stage_write(lds, tid, W4N, padw, wedge, 4, sr);

    __syncthreads();

    // ---- tile 1: planes r+2..r+4 ----
    tile_run(lds, bw, out, n, c0, MTN, hb + 2, /*plbase=*/r + 2, r, lm, q, f0, b0, b1);
}

extern "C" void kernel_launch(void* const* d_in, const int* in_sizes, int n_in,
                              void* d_out, int out_size, void* d_ws, size_t ws_size,
                              hipStream_t stream) {
    const float* x = (const float*)d_in[0];
    const float* w = (const float*)d_in[1];
    const float* b = (const float*)d_in[2];
    float* out = (float*)d_out;
    short* wbf = (short*)d_ws;   // 36864 shorts = 73728 B

    conv_wprep<<<144, 256, 0, stream>>>(w, wbf);   // 144*256 == 36864 exactly
    // grid: 896 blocks (~3.5/CU, 3 resident via 51.5 KB LDS). linear id % 8 ==
    // n % 8 keeps each image's blocks on one XCD for halo-row L2 reuse.
    dim3 grid(16, 2, 28);
    conv3x3_mfma<<<grid, 256, 0, stream>>>(x, wbf, b, out);
}

// Round 7
// 116.524 us; speedup vs baseline: 1.4945x; 1.4945x over previous
//
#include <hip/hip_runtime.h>

// Conv2d 3x3 s1 p1, N=16 C=64 H=W=112 F=64, fp32 in/out, bf16 MFMA implicit GEMM.
// R11 = R8 (best known: conv ~36us) + two local riders, nothing else changed:
//  (1) B-frags pinned in VGPRs via identity-asm ties. R8's VGPR=152 < 144
//      proves the compiler re-loaded B from L2 in the tap loop (~200cyc x 9/tile
//      exposed latency). Under (512,2) cap=256 the pinned ~220 regs FIT
//      (R10's spill disaster was the (256,3) cap=170, not the pin itself).
//  (2) lgkm-only barrier per tile: the only cross-wave dep is ds_write->ds_read.
//      __syncthreads drained vmcnt(0) = output stores (~500-900cyc) every tile;
//      now stores/prefetch stay in flight across barriers (T4 counted-vmcnt:
//      compiler still waits vmcnt before sr consumption in stage_write).
// Base structure (R8): 512-thread blocks (8 waves = 2/SIMD), persistent 14-row
// strips, NPL=8 plane ring (row&7), async stage split (loads before taps,
// convert+ds_write after), pitch-67 bank-uniform LDS, direct float4 epilogue.

typedef __attribute__((ext_vector_type(8))) short bf16x8;
typedef __attribute__((ext_vector_type(4))) float f32x4;

#define CIN 64
#define COUT 64
#define HH 112
#define WW 112
#define ROWS 2                    // output rows per tile
#define TILES 7                   // tiles per strip
#define STRIPH (ROWS * TILES)     // 14 rows per strip
#define NPL 8                     // ring planes (power of 2)
#define WPITCH 67                 // wcol pitch: 16B-unit residue (3*oct+w)&7 uniform
#define PLANE_SHORTS (8 * WPITCH * 8)    // 4288 shorts = 8576 B per plane
#define LDS_SHORTS (NPL * PLANE_SHORTS)  // 34304 shorts = 68608 B

__device__ __forceinline__ int ladr(int pl, int oct, int w) {
    // bf16 [plane][oct][wcol][8ch]; addr in shorts.
    return ((pl * 8 + oct) * WPITCH + w) * 8;
}

__device__ __forceinline__ unsigned short f2bf(float f) {
    unsigned u = __builtin_bit_cast(unsigned, f);
    u += 0x7FFFu + ((u >> 16) & 1u);   // round-to-nearest-even
    return (unsigned short)(u >> 16);
}

#if __has_builtin(__builtin_amdgcn_cvt_pk_bf16_f32)
__device__ __forceinline__ unsigned pk2bf(float a, float b) {
    typedef __attribute__((ext_vector_type(2))) __bf16 bf16x2;
    bf16x2 r = __builtin_amdgcn_cvt_pk_bf16_f32(a, b);
    return __builtin_bit_cast(unsigned, r);
}
#else
__device__ __forceinline__ unsigned pk2bf(float a, float b) {
    return (unsigned)f2bf(a) | ((unsigned)f2bf(b) << 16);
}
#endif

// lgkm-only barrier: ds_writes visible to all waves; vmcnt (stores + prefetch
// loads) stays in flight. sched_barrier fences per guide rule #18.
#define BAR_LGKM() do {                                   \
    __builtin_amdgcn_sched_barrier(0);                    \
    asm volatile("s_waitcnt lgkmcnt(0)" ::: "memory");    \
    __builtin_amdgcn_s_barrier();                         \
    __builtin_amdgcn_sched_barrier(0);                    \
} while (0)

// ---- one-time weight conversion: OIHW fp32 -> bf16 [t][cb][koct][f][j] ----
__global__ void conv_wprep(const float* __restrict__ w, short* __restrict__ wbf) {
    int i = blockIdx.x * 256 + threadIdx.x;    // grid sized to exactly 36864
    int j = i & 7;
    int f = (i >> 3) & 63;
    int koct = (i >> 9) & 3;
    int cb = (i >> 11) & 1;
    int t = i >> 12;
    int c = cb * 32 + koct * 8 + j;
    int ky = t / 3, kx = t - ky * 3;
    wbf[i] = (short)f2bf(w[((f * CIN + c) * 3 + ky) * 3 + kx]);
}

struct StageRegs {
    float4 v[8];   // interior unit: 8 channels x 4 cols (tid < 256)
    float hv;      // halo-column value (tid in [256,384))
};

// Issue global loads for a 2-row stage into regs. Wave-uniform branches:
// waves 0-3 = interior units (re,oct,w4); waves 4-5 = halo column.
__device__ __forceinline__ void stage_load(const float* __restrict__ x, int tid,
                                           int n, int c0, int W4N, int gce,
                                           int row0, StageRegs& sr)
{
    if (tid < 256) {
        const int re = tid >> 7, oct = (tid >> 4) & 7, w4 = tid & 15;
        const int row = row0 + re;
#pragma unroll
        for (int k = 0; k < 8; ++k) sr.v[k] = (float4){0.f, 0.f, 0.f, 0.f};
        if ((unsigned)row < (unsigned)HH && w4 < W4N) {
            const float* px = x + (((n * CIN + oct * 8) * HH + row) * WW + c0 + w4 * 4);
#pragma unroll
            for (int k = 0; k < 8; ++k) sr.v[k] = *(const float4*)(px + k * HH * WW);
        }
    } else if (tid < 384) {
        const int i = tid - 256;
        const int row = row0 + (i >> 6);
        sr.hv = 0.f;
        if ((unsigned)row < (unsigned)HH)
            sr.hv = x[((n * CIN + (i & 63)) * HH + row) * WW + gce];
    }
}

// Convert + write staged regs into ring planes (rows out of [0,HH) write zeros,
// which is exactly the padding the taps expect).
__device__ __forceinline__ void stage_write(short* lds, int tid, int W4N,
                                            int padw, int wedge, int row0,
                                            const StageRegs& sr)
{
    if (tid < 256) {
        const int re = tid >> 7, oct = (tid >> 4) & 7, w4 = tid & 15;
        const int pl = (row0 + re) & (NPL - 1);
        if (w4 < W4N) {
            const float* fv = (const float*)&sr.v[0];
#pragma unroll
            for (int dw = 0; dw < 4; ++dw) {
                uint4 pk;
                pk.x = pk2bf(fv[0 * 4 + dw], fv[1 * 4 + dw]);
                pk.y = pk2bf(fv[2 * 4 + dw], fv[3 * 4 + dw]);
                pk.z = pk2bf(fv[4 * 4 + dw], fv[5 * 4 + dw]);
                pk.w = pk2bf(fv[6 * 4 + dw], fv[7 * 4 + dw]);
                *(uint4*)&lds[ladr(pl, oct, 1 + w4 * 4 + dw)] = pk;
            }
        }
    } else if (tid < 384) {
        const int i = tid - 256;
        const int row = row0 + (i >> 6);
        const int pl = row & (NPL - 1);
        const int c = i & 63;
        lds[ladr(pl, c >> 3, wedge) + (c & 7)] = (short)f2bf(sr.hv);
    } else if (tid < 400) {
        const int i = tid - 384;
        const int pl = (row0 + (i >> 3)) & (NPL - 1);
        *(uint4*)&lds[ladr(pl, i & 7, padw)] = (uint4){0u, 0u, 0u, 0u};
    }
}

__global__ __launch_bounds__(512, 2)
void conv3x3_mfma(const float* __restrict__ x, const short* __restrict__ wbf,
                  const float* __restrict__ bias, float* __restrict__ out)
{
    __shared__ __align__(16) short lds[LDS_SHORTS];
    const int tid = threadIdx.x;
    const int n = blockIdx.x;
    const int ws = blockIdx.y;          // 0: out cols 0..63; 1: cols 64..111
    const int hb = blockIdx.z * STRIPH;

    const int MTN   = ws ? 3 : 4;
    const int W4N   = ws ? 12 : 16;
    const int c0    = ws * 64;
    const int padw  = ws ? 49 : 0;
    const int gce   = ws ? 63 : 64;
    const int wedge = ws ? 0 : 65;

    const int wave = tid >> 6;         // 0..7
    const int r  = wave >> 2;          // output row within tile (0..1)
    const int nh = (wave >> 1) & 1;    // cout half
    const int mh = wave & 1;           // mt half
    const int lane = tid & 63;
    const int lm = lane & 15;          // A: pixel m ; D: cout col
    const int q  = lane >> 4;          // k-octet index 0..3

    StageRegs sr;

    // ---- prologue: stage rows hb-1 .. hb+2 into ring slots ----
    stage_load(x, tid, n, c0, W4N, gce, hb - 1, sr);
    stage_write(lds, tid, W4N, padw, wedge, hb - 1, sr);
    stage_load(x, tid, n, c0, W4N, gce, hb + 1, sr);
    stage_write(lds, tid, W4N, padw, wedge, hb + 1, sr);

    // ---- B preload: 9 taps x 2 ntl x 2 cb = 36 frags (144 VGPR) ----
    bf16x8 bw[9][2][2];
#pragma unroll
    for (int t = 0; t < 9; ++t)
#pragma unroll
        for (int ntl = 0; ntl < 2; ++ntl) {
            const int f = nh * 32 + ntl * 16 + lm;
            bw[t][ntl][0] = *(const bf16x8*)(wbf + (t * 8 + q) * 512 + f * 8);
            bw[t][ntl][1] = *(const bf16x8*)(wbf + (t * 8 + 4 + q) * 512 + f * 8);
        }
    // Pin them: identity ties make remat/reload impossible. Fits (512,2) cap=256.
#pragma unroll
    for (int t = 0; t < 9; ++t)
#pragma unroll
        for (int ntl = 0; ntl < 2; ++ntl)
#pragma unroll
            for (int cb = 0; cb < 2; ++cb)
                asm volatile("" : "=v"(bw[t][ntl][cb]) : "0"(bw[t][ntl][cb]));

    const int f0 = nh * 32 + lm;
    const float b0 = bias[f0];
    const float b1 = bias[f0 + 16];

    BAR_LGKM();

    for (int t = 0; t < TILES; ++t) {
        const int h0 = hb + 2 * t;
        const bool do_stage = (t < TILES - 1);

        // issue next-tile loads early: latency hides under the tap loop
        if (do_stage) stage_load(x, tid, n, c0, W4N, gce, h0 + 3, sr);

        f32x4 acc[2][2];
#pragma unroll
        for (int j = 0; j < 2; ++j)
#pragma unroll
            for (int ntl = 0; ntl < 2; ++ntl) acc[j][ntl] = (f32x4){0.f, 0.f, 0.f, 0.f};

#pragma unroll
        for (int tap = 0; tap < 9; ++tap) {
            const int ky = tap / 3, kx = tap - ky * 3;
            const int pl = (h0 - 1 + r + ky) & (NPL - 1);
#pragma unroll
            for (int j = 0; j < 2; ++j) {
                const int mt = mh * 2 + j;
                if (mt < MTN) {
                    const int wcol = mt * 16 + lm + kx;
                    const bf16x8 a0 = *(const bf16x8*)&lds[ladr(pl, q, wcol)];
                    const bf16x8 a1 = *(const bf16x8*)&lds[ladr(pl, q + 4, wcol)];
                    acc[j][0] = __builtin_amdgcn_mfma_f32_16x16x32_bf16(a0, bw[tap][0][0], acc[j][0], 0, 0, 0);
                    acc[j][1] = __builtin_amdgcn_mfma_f32_16x16x32_bf16(a0, bw[tap][1][0], acc[j][1], 0, 0, 0);
                    acc[j][0] = __builtin_amdgcn_mfma_f32_16x16x32_bf16(a1, bw[tap][0][1], acc[j][0], 0, 0, 0);
                    acc[j][1] = __builtin_amdgcn_mfma_f32_16x16x32_bf16(a1, bw[tap][1][1], acc[j][1], 0, 0, 0);
                }
            }
        }

        // convert + LDS-write prefetched rows (planes h0+3,h0+4: no tap reads them)
        if (do_stage) stage_write(lds, tid, W4N, padw, wedge, h0 + 3, sr);

        // ---- epilogue: bias in-register, direct float4 stores ----
        const int hrow = h0 + r;
#pragma unroll
        for (int j = 0; j < 2; ++j) {
            const int mt = mh * 2 + j;
            if (mt < MTN) {
#pragma unroll
                for (int ntl = 0; ntl < 2; ++ntl) {
                    const f32x4 v = acc[j][ntl];
                    const float bb = ntl ? b1 : b0;
                    float4 s;
                    s.x = v[0] + bb; s.y = v[1] + bb; s.z = v[2] + bb; s.w = v[3] + bb;
                    *(float4*)(out + ((n * COUT + f0 + ntl * 16) * HH + hrow) * WW
                               + c0 + mt * 16 + q * 4) = s;
                }
            }
        }

        // ds_writes visible; stores + next loads stay in flight across barrier
        BAR_LGKM();
    }
}

extern "C" void kernel_launch(void* const* d_in, const int* in_sizes, int n_in,
                              void* d_out, int out_size, void* d_ws, size_t ws_size,
                              hipStream_t stream) {
    const float* x = (const float*)d_in[0];
    const float* w = (const float*)d_in[1];
    const float* b = (const float*)d_in[2];
    float* out = (float*)d_out;
    short* wbf = (short*)d_ws;   // 36864 shorts = 73728 B

    conv_wprep<<<144, 256, 0, stream>>>(w, wbf);   // 144*256 == 36864 exactly
    // grid: 256 blocks = 1/CU, 8 waves (2/SIMD). linear id % 8 == n % 8 keeps
    // each image's strip blocks on one XCD for halo-row L2 reuse.
    dim3 grid(16, 2, 8);
    conv3x3_mfma<<<grid, 512, 0, stream>>>(x, wbf, b, out);
}

// Round 8
// 116.229 us; speedup vs baseline: 1.4983x; 1.0025x over previous
//
#include <hip/hip_runtime.h>

// Conv2d 3x3 s1 p1, N=16 C=64 H=W=112 F=64, fp32 in/out, bf16 MFMA implicit GEMM.
// R12 = R11 + ONE change: #pragma unroll 1 on the tile loop.
// Theory: the compiler unrolls all 7 tiles -> ~25-80KB inner loop >> 32KB L1I;
// continuous I-fetch misses tax issue ~4x uniformly. Explains: (a) the stubborn
// conv ~42us across R5/R6/R8/R11 despite wildly different schedules/occupancy,
// (b) R7's 57us at 1 wave/SIMD (no TLP to hide I-fetch), (c) all pipes <20%.
// Keeping the tile body emitted ONCE (~3KB) fits I-cache.
// Base (R11): 512-thread blocks (8 waves = 2/SIMD), persistent 14-row strips,
// NPL=8 plane ring, async stage split, pinned B-frags (144 VGPR), lgkm-only
// barriers, pitch-67 bank-uniform LDS, direct float4 epilogue.

typedef __attribute__((ext_vector_type(8))) short bf16x8;
typedef __attribute__((ext_vector_type(4))) float f32x4;

#define CIN 64
#define COUT 64
#define HH 112
#define WW 112
#define ROWS 2                    // output rows per tile
#define TILES 7                   // tiles per strip
#define STRIPH (ROWS * TILES)     // 14 rows per strip
#define NPL 8                     // ring planes (power of 2)
#define WPITCH 67                 // wcol pitch: 16B-unit residue (3*oct+w)&7 uniform
#define PLANE_SHORTS (8 * WPITCH * 8)    // 4288 shorts = 8576 B per plane
#define LDS_SHORTS (NPL * PLANE_SHORTS)  // 34304 shorts = 68608 B

__device__ __forceinline__ int ladr(int pl, int oct, int w) {
    // bf16 [plane][oct][wcol][8ch]; addr in shorts.
    return ((pl * 8 + oct) * WPITCH + w) * 8;
}

__device__ __forceinline__ unsigned short f2bf(float f) {
    unsigned u = __builtin_bit_cast(unsigned, f);
    u += 0x7FFFu + ((u >> 16) & 1u);   // round-to-nearest-even
    return (unsigned short)(u >> 16);
}

#if __has_builtin(__builtin_amdgcn_cvt_pk_bf16_f32)
__device__ __forceinline__ unsigned pk2bf(float a, float b) {
    typedef __attribute__((ext_vector_type(2))) __bf16 bf16x2;
    bf16x2 r = __builtin_amdgcn_cvt_pk_bf16_f32(a, b);
    return __builtin_bit_cast(unsigned, r);
}
#else
__device__ __forceinline__ unsigned pk2bf(float a, float b) {
    return (unsigned)f2bf(a) | ((unsigned)f2bf(b) << 16);
}
#endif

// lgkm-only barrier: ds_writes visible to all waves; vmcnt (stores + prefetch
// loads) stays in flight. sched_barrier fences per guide rule #18.
#define BAR_LGKM() do {                                   \
    __builtin_amdgcn_sched_barrier(0);                    \
    asm volatile("s_waitcnt lgkmcnt(0)" ::: "memory");    \
    __builtin_amdgcn_s_barrier();                         \
    __builtin_amdgcn_sched_barrier(0);                    \
} while (0)

// ---- one-time weight conversion: OIHW fp32 -> bf16 [t][cb][koct][f][j] ----
__global__ void conv_wprep(const float* __restrict__ w, short* __restrict__ wbf) {
    int i = blockIdx.x * 256 + threadIdx.x;    // grid sized to exactly 36864
    int j = i & 7;
    int f = (i >> 3) & 63;
    int koct = (i >> 9) & 3;
    int cb = (i >> 11) & 1;
    int t = i >> 12;
    int c = cb * 32 + koct * 8 + j;
    int ky = t / 3, kx = t - ky * 3;
    wbf[i] = (short)f2bf(w[((f * CIN + c) * 3 + ky) * 3 + kx]);
}

struct StageRegs {
    float4 v[8];   // interior unit: 8 channels x 4 cols (tid < 256)
    float hv;      // halo-column value (tid in [256,384))
};

// Issue global loads for a 2-row stage into regs. Wave-uniform branches:
// waves 0-3 = interior units (re,oct,w4); waves 4-5 = halo column.
__device__ __forceinline__ void stage_load(const float* __restrict__ x, int tid,
                                           int n, int c0, int W4N, int gce,
                                           int row0, StageRegs& sr)
{
    if (tid < 256) {
        const int re = tid >> 7, oct = (tid >> 4) & 7, w4 = tid & 15;
        const int row = row0 + re;
#pragma unroll
        for (int k = 0; k < 8; ++k) sr.v[k] = (float4){0.f, 0.f, 0.f, 0.f};
        if ((unsigned)row < (unsigned)HH && w4 < W4N) {
            const float* px = x + (((n * CIN + oct * 8) * HH + row) * WW + c0 + w4 * 4);
#pragma unroll
            for (int k = 0; k < 8; ++k) sr.v[k] = *(const float4*)(px + k * HH * WW);
        }
    } else if (tid < 384) {
        const int i = tid - 256;
        const int row = row0 + (i >> 6);
        sr.hv = 0.f;
        if ((unsigned)row < (unsigned)HH)
            sr.hv = x[((n * CIN + (i & 63)) * HH + row) * WW + gce];
    }
}

// Convert + write staged regs into ring planes (rows out of [0,HH) write zeros,
// which is exactly the padding the taps expect).
__device__ __forceinline__ void stage_write(short* lds, int tid, int W4N,
                                            int padw, int wedge, int row0,
                                            const StageRegs& sr)
{
    if (tid < 256) {
        const int re = tid >> 7, oct = (tid >> 4) & 7, w4 = tid & 15;
        const int pl = (row0 + re) & (NPL - 1);
        if (w4 < W4N) {
            const float* fv = (const float*)&sr.v[0];
#pragma unroll
            for (int dw = 0; dw < 4; ++dw) {
                uint4 pk;
                pk.x = pk2bf(fv[0 * 4 + dw], fv[1 * 4 + dw]);
                pk.y = pk2bf(fv[2 * 4 + dw], fv[3 * 4 + dw]);
                pk.z = pk2bf(fv[4 * 4 + dw], fv[5 * 4 + dw]);
                pk.w = pk2bf(fv[6 * 4 + dw], fv[7 * 4 + dw]);
                *(uint4*)&lds[ladr(pl, oct, 1 + w4 * 4 + dw)] = pk;
            }
        }
    } else if (tid < 384) {
        const int i = tid - 256;
        const int row = row0 + (i >> 6);
        const int pl = row & (NPL - 1);
        const int c = i & 63;
        lds[ladr(pl, c >> 3, wedge) + (c & 7)] = (short)f2bf(sr.hv);
    } else if (tid < 400) {
        const int i = tid - 384;
        const int pl = (row0 + (i >> 3)) & (NPL - 1);
        *(uint4*)&lds[ladr(pl, i & 7, padw)] = (uint4){0u, 0u, 0u, 0u};
    }
}

__global__ __launch_bounds__(512, 2)
void conv3x3_mfma(const float* __restrict__ x, const short* __restrict__ wbf,
                  const float* __restrict__ bias, float* __restrict__ out)
{
    __shared__ __align__(16) short lds[LDS_SHORTS];
    const int tid = threadIdx.x;
    const int n = blockIdx.x;
    const int ws = blockIdx.y;          // 0: out cols 0..63; 1: cols 64..111
    const int hb = blockIdx.z * STRIPH;

    const int MTN   = ws ? 3 : 4;
    const int W4N   = ws ? 12 : 16;
    const int c0    = ws * 64;
    const int padw  = ws ? 49 : 0;
    const int gce   = ws ? 63 : 64;
    const int wedge = ws ? 0 : 65;

    const int wave = tid >> 6;         // 0..7
    const int r  = wave >> 2;          // output row within tile (0..1)
    const int nh = (wave >> 1) & 1;    // cout half
    const int mh = wave & 1;           // mt half
    const int lane = tid & 63;
    const int lm = lane & 15;          // A: pixel m ; D: cout col
    const int q  = lane >> 4;          // k-octet index 0..3

    StageRegs sr;

    // ---- prologue: stage rows hb-1 .. hb+2 into ring slots ----
    stage_load(x, tid, n, c0, W4N, gce, hb - 1, sr);
    stage_write(lds, tid, W4N, padw, wedge, hb - 1, sr);
    stage_load(x, tid, n, c0, W4N, gce, hb + 1, sr);
    stage_write(lds, tid, W4N, padw, wedge, hb + 1, sr);

    // ---- B preload: 9 taps x 2 ntl x 2 cb = 36 frags (144 VGPR) ----
    bf16x8 bw[9][2][2];
#pragma unroll
    for (int t = 0; t < 9; ++t)
#pragma unroll
        for (int ntl = 0; ntl < 2; ++ntl) {
            const int f = nh * 32 + ntl * 16 + lm;
            bw[t][ntl][0] = *(const bf16x8*)(wbf + (t * 8 + q) * 512 + f * 8);
            bw[t][ntl][1] = *(const bf16x8*)(wbf + (t * 8 + 4 + q) * 512 + f * 8);
        }
    // Pin them: identity ties make remat/reload impossible. Fits (512,2) cap=256.
#pragma unroll
    for (int t = 0; t < 9; ++t)
#pragma unroll
        for (int ntl = 0; ntl < 2; ++ntl)
#pragma unroll
            for (int cb = 0; cb < 2; ++cb)
                asm volatile("" : "=v"(bw[t][ntl][cb]) : "0"(bw[t][ntl][cb]));

    const int f0 = nh * 32 + lm;
    const float b0 = bias[f0];
    const float b1 = bias[f0 + 16];

    BAR_LGKM();

    // R12 CHANGE: forbid tile-loop unrolling -> tile body emitted once (~3KB),
    // stays I-cache resident (was ~7x replicated -> L1I thrash).
#pragma unroll 1
    for (int t = 0; t < TILES; ++t) {
        const int h0 = hb + 2 * t;
        const bool do_stage = (t < TILES - 1);

        // issue next-tile loads early: latency hides under the tap loop
        if (do_stage) stage_load(x, tid, n, c0, W4N, gce, h0 + 3, sr);

        f32x4 acc[2][2];
#pragma unroll
        for (int j = 0; j < 2; ++j)
#pragma unroll
            for (int ntl = 0; ntl < 2; ++ntl) acc[j][ntl] = (f32x4){0.f, 0.f, 0.f, 0.f};

#pragma unroll
        for (int tap = 0; tap < 9; ++tap) {
            const int ky = tap / 3, kx = tap - ky * 3;
            const int pl = (h0 - 1 + r + ky) & (NPL - 1);
#pragma unroll
            for (int j = 0; j < 2; ++j) {
                const int mt = mh * 2 + j;
                if (mt < MTN) {
                    const int wcol = mt * 16 + lm + kx;
                    const bf16x8 a0 = *(const bf16x8*)&lds[ladr(pl, q, wcol)];
                    const bf16x8 a1 = *(const bf16x8*)&lds[ladr(pl, q + 4, wcol)];
                    acc[j][0] = __builtin_amdgcn_mfma_f32_16x16x32_bf16(a0, bw[tap][0][0], acc[j][0], 0, 0, 0);
                    acc[j][1] = __builtin_amdgcn_mfma_f32_16x16x32_bf16(a0, bw[tap][1][0], acc[j][1], 0, 0, 0);
                    acc[j][0] = __builtin_amdgcn_mfma_f32_16x16x32_bf16(a1, bw[tap][0][1], acc[j][0], 0, 0, 0);
                    acc[j][1] = __builtin_amdgcn_mfma_f32_16x16x32_bf16(a1, bw[tap][1][1], acc[j][1], 0, 0, 0);
                }
            }
        }

        // convert + LDS-write prefetched rows (planes h0+3,h0+4: no tap reads them)
        if (do_stage) stage_write(lds, tid, W4N, padw, wedge, h0 + 3, sr);

        // ---- epilogue: bias in-register, direct float4 stores ----
        const int hrow = h0 + r;
#pragma unroll
        for (int j = 0; j < 2; ++j) {
            const int mt = mh * 2 + j;
            if (mt < MTN) {
#pragma unroll
                for (int ntl = 0; ntl < 2; ++ntl) {
                    const f32x4 v = acc[j][ntl];
                    const float bb = ntl ? b1 : b0;
                    float4 s;
                    s.x = v[0] + bb; s.y = v[1] + bb; s.z = v[2] + bb; s.w = v[3] + bb;
                    *(float4*)(out + ((n * COUT + f0 + ntl * 16) * HH + hrow) * WW
                               + c0 + mt * 16 + q * 4) = s;
                }
            }
        }

        // ds_writes visible; stores + next loads stay in flight across barrier
        BAR_LGKM();
    }
}

extern "C" void kernel_launch(void* const* d_in, const int* in_sizes, int n_in,
                              void* d_out, int out_size, void* d_ws, size_t ws_size,
                              hipStream_t stream) {
    const float* x = (const float*)d_in[0];
    const float* w = (const float*)d_in[1];
    const float* b = (const float*)d_in[2];
    float* out = (float*)d_out;
    short* wbf = (short*)d_ws;   // 36864 shorts = 73728 B

    conv_wprep<<<144, 256, 0, stream>>>(w, wbf);   // 144*256 == 36864 exactly
    // grid: 256 blocks = 1/CU, 8 waves (2/SIMD). linear id % 8 == n % 8 keeps
    // each image's strip blocks on one XCD for halo-row L2 reuse.
    dim3 grid(16, 2, 8);
    conv3x3_mfma<<<grid, 512, 0, stream>>>(x, wbf, b, out);
}